// Round 8
// baseline (169.256 us; speedup 1.0000x reference)
//
#include <hip/hip_runtime.h>

#define BATCH   16384
#define NUM_NUM 32
#define NUM_CAT 32
#define CARD    128
#define OUT_F   32
#define XSTRIDE 4128   // NUM_NUM + NUM_CAT*CARD
#define OSTRIDE 1056   // NUM_NUM + NUM_CAT*OUT_F

// Batched-GEMV formulation: thread = (row, f). Each thread reads its row's 512B
// x-slice (32 float4; lane stride 16.5KB, but every 64B line fully consumed across
// 4 consecutive c4 instrs via L1 -> zero over-fetch) and computes all 32 outputs.
// W[f] is block-uniform -> s_load_dwordx4 stream on the SMEM pipe (1024/wave-f vs
// 8192 FMA cyc). NO LDS, NO barriers, NO staging: pure TLP latency hiding.
// Consecutive blocks share f (grid.x fastest) -> W hot in K$/L2.
__global__ __launch_bounds__(256, 4) void emb_gemv(const float* __restrict__ x,
                                                   const float* __restrict__ Wm,
                                                   const float* __restrict__ bias,
                                                   float* __restrict__ out) {
    const int f   = blockIdx.y;
    const int row = blockIdx.x * 256 + threadIdx.x;

    // wave-uniform W quad pointer: wq[c*8 + q] = W[f][c][q*4 .. q*4+4)
    const float4* __restrict__ wq = (const float4*)(Wm + (size_t)f * (CARD * OUT_F));
    const float*  __restrict__ xr = x + (size_t)row * XSTRIDE + NUM_NUM + f * CARD;

    float acc[32];
#pragma unroll
    for (int k = 0; k < 32; ++k) acc[k] = 0.0f;

#pragma unroll 2
    for (int c4 = 0; c4 < CARD / 4; ++c4) {
        const float4 xv = *(const float4*)(xr + c4 * 4);
#pragma unroll
        for (int cc = 0; cc < 4; ++cc) {
            const float xf = (&xv.x)[cc];
#pragma unroll
            for (int q = 0; q < 8; ++q) {
                const float4 w = wq[(c4 * 4 + cc) * 8 + q];  // s_load_dwordx4 (uniform)
                acc[q * 4 + 0] += xf * w.x;
                acc[q * 4 + 1] += xf * w.y;
                acc[q * 4 + 2] += xf * w.z;
                acc[q * 4 + 3] += xf * w.w;
            }
        }
    }

    // epilogue: bias (uniform, SGPR) + 8 float4 stores = exactly 2 full 64B lines/lane
    const float4* __restrict__ bq = (const float4*)(bias + f * OUT_F);
    float* orow = out + (size_t)row * OSTRIDE + NUM_NUM + f * OUT_F;
#pragma unroll
    for (int q = 0; q < 8; ++q) {
        const float4 b = bq[q];
        float4       o;
        o.x = acc[q * 4 + 0] + b.x;
        o.y = acc[q * 4 + 1] + b.y;
        o.z = acc[q * 4 + 2] + b.z;
        o.w = acc[q * 4 + 3] + b.w;
        *(float4*)(orow + q * 4) = o;
    }

    // numeric passthrough folded into f==0 blocks: each thread copies its row's
    // first 32 floats (2 full 64B lines, base 64B-aligned).
    if (f == 0) {
        const float4* src = (const float4*)(x + (size_t)row * XSTRIDE);
        float4*       dst = (float4*)(out + (size_t)row * OSTRIDE);
#pragma unroll
        for (int q = 0; q < 8; ++q) dst[q] = src[q];
    }
}

extern "C" void kernel_launch(void* const* d_in, const int* in_sizes, int n_in,
                              void* d_out, int out_size, void* d_ws, size_t ws_size,
                              hipStream_t stream) {
    const float* x    = (const float*)d_in[0];
    const float* W    = (const float*)d_in[1];
    const float* bias = (const float*)d_in[2];
    float*       out  = (float*)d_out;

    dim3 grid(BATCH / 256, NUM_CAT);  // (64, 32); grid.x fastest -> same-f blocks adjacent
    emb_gemv<<<grid, 256, 0, stream>>>(x, W, bias, out);
}

// Round 9
// 92.817 us; speedup vs baseline: 1.8235x; 1.8235x over previous
//
#include <hip/hip_runtime.h>

#define BATCH   16384
#define NUM_NUM 32
#define NUM_CAT 32
#define CARD    128
#define OUT_F   32
#define XSTRIDE 4128   // NUM_NUM + NUM_CAT*CARD
#define OSTRIDE 1056   // NUM_NUM + NUM_CAT*OUT_F

#define TRB 64   // rows per block; x_s = 64 rows x 32 quads = 32 KB

typedef const __attribute__((address_space(1))) void* as1_cvp;
typedef __attribute__((address_space(3))) void*       as3_vp;

// Block = (feature f, 64-row stripe). 256 thr = 4 waves. FULL-K staging: one
// 32KB LDS buffer, ONE stage barrier per block (no K-chunks, no dbuf).
// Grid f-fastest: 32 consecutive blocks read one contiguous 1MB x-stripe ->
// sequential HBM streaming at max DRAM granule (512B/row contiguous).
// x_s swizzle: logical quad Q = row*32 + c4, phys = Q ^ ((Q>>5)&7) (XOR bits 0-2;
// (Q>>5)==row preserved -> involution).
//   compute read (fixed c4): lane l reads phys l*32+(c4^(l&7)) -> per 16-lane
//   phase bank-quads c4^0..7 twice = 2-way (free).
//   stage instr i (8/wave): lane l -> phys P=64i+l -> row 2i+(l>>5),
//   cq (l&31)^((2i+(l>>5))&7): 32 lanes cover one row's 512B permuted -> coalesced.
// W via wave-uniform s_load_dwordx4 (og = tid>>6): SMEM pipe, off LDS entirely.
// Per-thread state acc[8] -> no fission (r8 lesson), no spill.
// Per-CU budget @5 blocks: mem 15.6K cyc > VALU 10.2K > LDS 7.7K -> memory-paced.
__global__ __launch_bounds__(256, 5) void emb_gemv(const float* __restrict__ x,
                                                   const float* __restrict__ Wm,
                                                   const float* __restrict__ bias,
                                                   float* __restrict__ out) {
    __shared__ float4 x_s[TRB * (CARD / 4)];  // 2048 quads, 32 KB

    const int f    = blockIdx.x;
    const int row0 = blockIdx.y * TRB;
    const int tid  = threadIdx.x;
    const int l    = tid & 63;
    const int lx   = l & 7;
    const int og   = __builtin_amdgcn_readfirstlane(tid >> 6);  // wave out-group

    const float* xg = x + (size_t)row0 * XSTRIDE + NUM_NUM + f * CARD;

    // ---- stage: 8 global_load_lds per thread, linear dest, inv-swizzled source ----
#pragma unroll
    for (int s = 0; s < 8; ++s) {
        const int i   = og * 8 + s;               // stage instr index 0..31
        const int row = 2 * i + (l >> 5);
        const int cq  = (l & 31) ^ ((2 * i + (l >> 5)) & 7);
        __builtin_amdgcn_global_load_lds((as1_cvp)(xg + row * XSTRIDE + cq * 4),
                                         (as3_vp)&x_s[i * 64 + l], 16, 0, 0);
    }
    __syncthreads();

    // wave-uniform W quad pointer: this wave needs quads c*8 + og*2 {+1}
    const float4* __restrict__ wq =
        (const float4*)Wm + ((size_t)f * (CARD * OUT_F / 4) + og * 2);

    float acc[8];
#pragma unroll
    for (int k = 0; k < 8; ++k) acc[k] = 0.0f;

#pragma unroll 4
    for (int c4 = 0; c4 < CARD / 4; ++c4) {
        const float4 xv = x_s[l * 32 + (c4 ^ lx)];  // logical quad c4 of row l
#pragma unroll
        for (int cc = 0; cc < 4; ++cc) {
            const int    c  = c4 * 4 + cc;
            const float4 wa = wq[c * 8];      // s_load_dwordx4 (uniform)
            const float4 wb = wq[c * 8 + 1];
            const float  xf = (&xv.x)[cc];
            acc[0] += xf * wa.x;  acc[1] += xf * wa.y;
            acc[2] += xf * wa.z;  acc[3] += xf * wa.w;
            acc[4] += xf * wb.x;  acc[5] += xf * wb.y;
            acc[6] += xf * wb.z;  acc[7] += xf * wb.w;
        }
    }
    __syncthreads();  // all x_s reads done; buffer reusable for C-transpose

    // ---- transpose C through LDS: 64 rows x 8 quads, swizzle Q^((Q>>3)&7) ----
#pragma unroll
    for (int k = 0; k < 2; ++k)
        x_s[l * 8 + ((og * 2 + k) ^ lx)] =
            make_float4(acc[k * 4], acc[k * 4 + 1], acc[k * 4 + 2], acc[k * 4 + 3]);
    __syncthreads();

#pragma unroll
    for (int p = 0; p < 2; ++p) {
        const int    r = p * 32 + (tid >> 3);   // 0..63
        const int    q = tid & 7;
        float4       v = x_s[r * 8 + (q ^ (r & 7))];
        const float4 b = ((const float4*)bias)[f * 8 + q];
        v.x += b.x; v.y += b.y; v.z += b.z; v.w += b.w;
        *(float4*)(out + (size_t)(row0 + r) * OSTRIDE + NUM_NUM + f * OUT_F + q * 4) = v;
    }

    // ---- numeric passthrough: f==0 block of each stripe copies rows' first 32 cols ----
    if (f == 0) {
#pragma unroll
        for (int it = 0; it < 2; ++it) {
            const int idx = it * 256 + tid;     // 512 float4
            const int r   = idx >> 3;
            const int c4  = (idx & 7) << 2;
            *(float4*)(out + (size_t)(row0 + r) * OSTRIDE + c4) =
                *(const float4*)(x + (size_t)(row0 + r) * XSTRIDE + c4);
        }
    }
}

extern "C" void kernel_launch(void* const* d_in, const int* in_sizes, int n_in,
                              void* d_out, int out_size, void* d_ws, size_t ws_size,
                              hipStream_t stream) {
    const float* x    = (const float*)d_in[0];
    const float* W    = (const float*)d_in[1];
    const float* bias = (const float*)d_in[2];
    float*       out  = (float*)d_out;

    dim3 grid(NUM_CAT, BATCH / TRB);  // (32, 256), f fastest -> contiguous x stripes
    emb_gemv<<<grid, 256, 0, stream>>>(x, W, bias, out);
}